// Round 1
// 2378.190 us; speedup vs baseline: 1.1238x; 1.1238x over previous
//
#include <hip/hip_runtime.h>
#include <math.h>

// B=4096, S=64, H=256, 2 GRU layers.
// Cluster design: 32 clusters x 8 WGs (=256 WGs, 1/CU forced by LDS).
// Each WG owns a 32-unit slice of H for its cluster's 128 batch rows; its
// weight slice (3 x 96x256 fp16 = 144 KB) lives in LDS for the whole kernel.
// h0/h1 are exchanged via global (double-buffered), 2 cluster barriers/step.
#define NCL 32     // clusters
#define CW  8      // WGs per cluster
#define BTC 128    // batch rows per cluster
#define NT  512    // 8 waves: wave w -> (mp=w>>1 row-block of 32, hv=w&1 unit-subtile of 16)
#define SS  64
#define HH  256

typedef __attribute__((ext_vector_type(8))) _Float16 half8;
typedef __attribute__((ext_vector_type(4))) float    f32x4;

__device__ __forceinline__ float sigmoidf_(float v){ return 1.0f/(1.0f+expf(-v)); }

// LDS weight block layout: halfs offset = mat*24576 + ntl*4096 + kt*512 + lane*8
// mat: 0=Whh0 1=Wih1 2=Whh1 ; ntl = type*2 + usub (type 0=r,1=z,2=n)
#define WOFF(mat,ntl,kt) ((mat)*24576 + (ntl)*4096 + (kt)*512)

__global__ void zero_flags(int* f){
    int i = blockIdx.x*blockDim.x + threadIdx.x;
    if (i < NCL*SS*2) f[i] = 0;
}

__device__ __forceinline__ void cluster_barrier(int* flag){
    __syncthreads();                       // drains vmcnt for all threads (stores done)
    if (threadIdx.x == 0){
        __threadfence();                   // release to device scope
        __hip_atomic_fetch_add(flag, 1, __ATOMIC_RELAXED, __HIP_MEMORY_SCOPE_AGENT);
        int guard = 0;
        while (__hip_atomic_load(flag, __ATOMIC_RELAXED, __HIP_MEMORY_SCOPE_AGENT) < CW){
            __builtin_amdgcn_s_sleep(2);
            if (++guard > (1<<16)) break;  // safety: never hang the harness
        }
        __threadfence();                   // acquire: invalidate CU L1 / XCD L2
    }
    __syncthreads();
}

__global__ __launch_bounds__(NT,2) void rnn_cluster(
    const int*   __restrict__ x,      // (B,S) in {-1,+1}
    const float* __restrict__ Wih0,   // (768,2)
    const float* __restrict__ Whh0,   // (768,256)
    const float* __restrict__ Wih1,   // (768,256)
    const float* __restrict__ Whh1,   // (768,256)
    const float* __restrict__ Wl,     // (2,256)
    const float* __restrict__ bl,     // (2,)
    float*       __restrict__ out,    // (B,) real(wf)
    int*         __restrict__ flags,  // (NCL, SS, 2) zeroed per launch
    _Float16*    __restrict__ Hbuf)   // 2 layers x NCL x 2 bufs x 128x256 halfs
{
    __shared__ _Float16 wlds[3*6*8*64*8];          // 147456 B weight slice
    __shared__ unsigned long long bitsM[BTC];      // 1 KB bit masks

    const int t   = threadIdx.x;
    const int c   = blockIdx.x & (NCL-1);          // cluster id
    const int j   = blockIdx.x >> 5;               // member 0..7 (bid=c+32j: same XCD)
    const int L   = t & 63;
    const int w   = t >> 6;
    const int lm  = L & 15, quad = L >> 4;
    const int mp  = w >> 1, hv = w & 1;

    _Float16* H0 = Hbuf + (size_t)c*(2*BTC*HH);
    _Float16* H1 = Hbuf + (size_t)(NCL + c)*(2*BTC*HH);
    int* flg = flags + c*(SS*2);

    // ---- pack this WG's weight slice into LDS (once) ----
    for (int idx = t; idx < 3*6*8*64; idx += NT){
        int lane = idx & 63;
        int kt   = (idx >> 6) & 7;
        int ntl  = (idx >> 9) % 6;
        int mat  = idx / 3072;
        const float* W = (mat==0) ? Whh0 : (mat==1) ? Wih1 : Whh1;
        int g  = (ntl>>1)*HH + j*32 + (ntl&1)*16 + (lane & 15);
        int kb = kt*32 + (lane>>4)*8;
        _Float16* d = wlds + (size_t)idx*8;
        #pragma unroll
        for (int e=0;e<8;++e) d[e] = (_Float16)W[g*HH + kb + e];
    }
    if (t < BTC){
        unsigned long long m = 0;
        const int* xr = x + (size_t)(c*BTC + t)*SS;
        for (int s=0;s<SS;++s) if (xr[s] > 0) m |= (1ull<<s);
        bitsM[t] = m;
    }

    // layer-0 input-gate weights for this lane's owned unit
    float g0w[6];
    { int ug = j*32 + hv*16 + lm;
      g0w[0]=Wih0[ug*2+0];        g0w[1]=Wih0[ug*2+1];
      g0w[2]=Wih0[(ug+HH)*2+0];   g0w[3]=Wih0[(ug+HH)*2+1];
      g0w[4]=Wih0[(ug+2*HH)*2+0]; g0w[5]=Wih0[(ug+2*HH)*2+1]; }

    // sampling: this thread's row (16 rows/WG, 32 lanes cooperate per row)
    const int srow = j*16 + (t>>5);
    const int cs   = t & 31;
    float wl0[8], wl1[8];
    #pragma unroll
    for (int e=0;e<8;++e){ wl0[e]=Wl[cs*8+e]; wl1[e]=Wl[HH+cs*8+e]; }
    const float bl0=bl[0], bl1=bl[1];

    float hr0[2][4] = {}, hr1[2][4] = {};
    float amp=1.f, ph=0.f, nup=0.f, ndn=0.f;

    __syncthreads();

    for (int step=0; step<SS; ++step){
        const int cur = step & 1, nxt = cur ^ 1;

        // ---------------- GEMM0: gh0 = h0 @ Whh0^T ----------------
        f32x4 a0[3][2] = {};
        if (step > 0){
            const _Float16* Hs = H0 + cur*(BTC*HH) + (32*mp + lm)*HH;
            half8 A[8][2];
            #pragma unroll
            for (int kt=0;kt<8;++kt){
                A[kt][0] = *(const half8*)(Hs +           kt*32 + quad*8);
                A[kt][1] = *(const half8*)(Hs + 16*HH +   kt*32 + quad*8);
            }
            #pragma unroll
            for (int kt=0;kt<8;++kt){
                #pragma unroll
                for (int ty=0;ty<3;++ty){
                    half8 Bv = *(const half8*)(wlds + WOFF(0, ty*2+hv, kt) + L*8);
                    #pragma unroll
                    for (int m2=0;m2<2;++m2)
                        a0[ty][m2] = __builtin_amdgcn_mfma_f32_16x16x32_f16(A[kt][m2], Bv, a0[ty][m2],0,0,0);
                }
            }
        }

        // ---------------- ew0 + write h0n slice ----------------
        {
            _Float16* wp = H0 + nxt*(BTC*HH) + (32*mp + 4*quad)*HH + (j*32 + hv*16 + lm);
            #pragma unroll
            for (int m2=0;m2<2;++m2){
                #pragma unroll
                for (int reg=0;reg<4;++reg){
                    int rowL = 32*mp + 16*m2 + 4*quad + reg;
                    float gr=0.f, gz=0.f, gn=0.f;
                    if (step > 0){
                        int bit = (int)((bitsM[rowL] >> (step-1)) & 1ull);
                        gr = bit ? g0w[1] : g0w[0];
                        gz = bit ? g0w[3] : g0w[2];
                        gn = bit ? g0w[5] : g0w[4];
                    }
                    float r = sigmoidf_(gr + a0[0][m2][reg]);
                    float z = sigmoidf_(gz + a0[1][m2][reg]);
                    float n = tanhf(gn + r*a0[2][m2][reg]);
                    float hnew = (1.f-z)*n + z*hr0[m2][reg];
                    hr0[m2][reg] = hnew;
                    wp[(16*m2 + reg)*HH] = (_Float16)hnew;
                }
            }
        }
        cluster_barrier(&flg[step*2 + 0]);   // h0n visible cluster-wide

        // ------- GEMM1: gi1 = h0n@Wih1^T ; gh1 = h1@Whh1^T -------
        f32x4 aR[2]={}, aZ[2]={}, aNI[2]={}, aNH[2]={};
        {
            const _Float16* Hs = H0 + nxt*(BTC*HH) + (32*mp + lm)*HH;
            half8 A[8][2];
            #pragma unroll
            for (int kt=0;kt<8;++kt){
                A[kt][0] = *(const half8*)(Hs +         kt*32 + quad*8);
                A[kt][1] = *(const half8*)(Hs + 16*HH + kt*32 + quad*8);
            }
            #pragma unroll
            for (int kt=0;kt<8;++kt){
                half8 Br = *(const half8*)(wlds + WOFF(1, 0+hv, kt) + L*8);
                half8 Bz = *(const half8*)(wlds + WOFF(1, 2+hv, kt) + L*8);
                half8 Bn = *(const half8*)(wlds + WOFF(1, 4+hv, kt) + L*8);
                #pragma unroll
                for (int m2=0;m2<2;++m2){
                    aR [m2] = __builtin_amdgcn_mfma_f32_16x16x32_f16(A[kt][m2], Br, aR [m2],0,0,0);
                    aZ [m2] = __builtin_amdgcn_mfma_f32_16x16x32_f16(A[kt][m2], Bz, aZ [m2],0,0,0);
                    aNI[m2] = __builtin_amdgcn_mfma_f32_16x16x32_f16(A[kt][m2], Bn, aNI[m2],0,0,0);
                }
            }
        }
        if (step > 0){
            const _Float16* Hs = H1 + cur*(BTC*HH) + (32*mp + lm)*HH;
            half8 A[8][2];
            #pragma unroll
            for (int kt=0;kt<8;++kt){
                A[kt][0] = *(const half8*)(Hs +         kt*32 + quad*8);
                A[kt][1] = *(const half8*)(Hs + 16*HH + kt*32 + quad*8);
            }
            #pragma unroll
            for (int kt=0;kt<8;++kt){
                half8 Br = *(const half8*)(wlds + WOFF(2, 0+hv, kt) + L*8);
                half8 Bz = *(const half8*)(wlds + WOFF(2, 2+hv, kt) + L*8);
                half8 Bn = *(const half8*)(wlds + WOFF(2, 4+hv, kt) + L*8);
                #pragma unroll
                for (int m2=0;m2<2;++m2){
                    aR [m2] = __builtin_amdgcn_mfma_f32_16x16x32_f16(A[kt][m2], Br, aR [m2],0,0,0);
                    aZ [m2] = __builtin_amdgcn_mfma_f32_16x16x32_f16(A[kt][m2], Bz, aZ [m2],0,0,0);
                    aNH[m2] = __builtin_amdgcn_mfma_f32_16x16x32_f16(A[kt][m2], Bn, aNH[m2],0,0,0);
                }
            }
        }

        // ---------------- ew1 + write h1n slice ----------------
        {
            _Float16* wp = H1 + nxt*(BTC*HH) + (32*mp + 4*quad)*HH + (j*32 + hv*16 + lm);
            #pragma unroll
            for (int m2=0;m2<2;++m2){
                #pragma unroll
                for (int reg=0;reg<4;++reg){
                    float r = sigmoidf_(aR[m2][reg]);
                    float z = sigmoidf_(aZ[m2][reg]);
                    float n = tanhf(aNI[m2][reg] + r*aNH[m2][reg]);
                    float hnew = (1.f-z)*n + z*hr1[m2][reg];
                    hr1[m2][reg] = hnew;
                    wp[(16*m2 + reg)*HH] = (_Float16)hnew;
                }
            }
        }
        cluster_barrier(&flg[step*2 + 1]);   // h1n visible cluster-wide

        // ---------------- logits + sampling (16 rows/WG, 32 lanes/row) ----------------
        {
            const _Float16* Hn = H1 + nxt*(BTC*HH) + srow*HH;
            half8 hvv = *(const half8*)(Hn + cs*8);
            float s0=0.f, s1=0.f;
            #pragma unroll
            for (int e=0;e<8;++e){
                float f = (float)hvv[e];
                s0 += f*wl0[e];
                s1 += f*wl1[e];
            }
            #pragma unroll
            for (int off=16; off>0; off>>=1){
                s0 += __shfl_xor(s0, off, 32);
                s1 += __shfl_xor(s1, off, 32);
            }
            float l0 = s0 + bl0, l1 = s1 + bl1;

            bool  ev  = (step & 1) == 0;
            float low = -16.f + (float)(step>>1);
            float cnt = ev ? nup : ndn;
            float mocc = (16.f > cnt) ? 1.f : 0.f;
            float mun  = (low  < cnt) ? 1.f : 0.f;

            float mx = fmaxf(l0,l1);
            float e0 = expf(l0-mx), e1 = expf(l1-mx);
            float inv = 1.f/(e0+e1);
            float a0s = sqrtf(e0*inv)*mun;
            float a1s = sqrtf(e1*inv)*mocc;
            float nrm = sqrtf(a0s*a0s + a1s*a1s);
            float den = fmaxf(nrm, 1e-12f);
            a0s/=den; a1s/=den;

            const float PI_F = 3.14159265358979323846f;
            float p0 = PI_F*l0/(1.f+fabsf(l0));
            float p1 = PI_F*l1/(1.f+fabsf(l1));

            int bit = (int)((bitsM[srow] >> step) & 1ull);
            amp *= bit ? a1s : a0s;
            ph  += bit ? p1 : p0;
            if (ev) nup += (float)bit; else ndn += (float)bit;
        }
    }

    if (cs == 0) out[c*BTC + srow] = amp * cosf(ph);
}

extern "C" void kernel_launch(void* const* d_in, const int* in_sizes, int n_in,
                              void* d_out, int out_size, void* d_ws, size_t ws_size,
                              hipStream_t stream) {
    (void)in_sizes; (void)n_in; (void)out_size; (void)ws_size;
    const int*   x    = (const int*)d_in[0];
    const float* Wih0 = (const float*)d_in[1];
    const float* Whh0 = (const float*)d_in[2];
    const float* Wih1 = (const float*)d_in[3];
    const float* Whh1 = (const float*)d_in[4];
    const float* Wl   = (const float*)d_in[5];
    const float* bl   = (const float*)d_in[6];

    int*      flags = (int*)d_ws;                            // 16 KB, zeroed each launch
    _Float16* Hbuf  = (_Float16*)((char*)d_ws + 65536);      // 8 MB h state

    zero_flags<<<(NCL*SS*2 + 255)/256, 256, 0, stream>>>(flags);
    rnn_cluster<<<NCL*CW, NT, 0, stream>>>(x, Wih0, Whh0, Wih1, Whh1, Wl, bl,
                                           (float*)d_out, flags, Hbuf);
}

// Round 2
// 1467.195 us; speedup vs baseline: 1.8216x; 1.6209x over previous
//
#include <hip/hip_runtime.h>
#include <math.h>

// B=4096, S=64, H=256, 2 GRU layers.
// 32 clusters x 8 WGs (=256 WGs, 1/CU). Weight slice (144 KB fp16) LDS-resident.
// Software-pipelined: layer0 runs one step ahead of layer1 so each step needs
// only ONE cluster barrier and ONE fused {A-load -> 3 GEMMs} phase.
// Interval i (entering: h0n(i), h1n(i-1) published):
//   sampling(i-1); load A0=h0n(i), A1=h1n(i-1);
//   gh0(i+1)=A0@Whh0, gi1(i)=A0@Wih1, gh1(i)=A1@Whh1;
//   ew1(i)->h1n(i)->H1[i&1]; ew0(i+1)->h0n(i+1)->H0[(i+1)&1]; arrive bar(i).
#define NCL 32
#define CW  8
#define BTC 128
#define NT  512
#define SS  64
#define HH  256

typedef __attribute__((ext_vector_type(8))) _Float16 half8;
typedef __attribute__((ext_vector_type(4))) float    f32x4;

__device__ __forceinline__ float sigmoidf_(float v){ return 1.0f/(1.0f+expf(-v)); }

// LDS weight layout: halfs offset = mat*24576 + ntl*4096 + kt*512 + lane*8
// mat: 0=Whh0 1=Wih1 2=Whh1 ; ntl = type*2 + hv (type 0=r,1=z,2=n)
#define WOFF(mat,ntl,kt) ((mat)*24576 + (ntl)*4096 + (kt)*512)

__global__ void zero_flags(int* f){
    int i = blockIdx.x*blockDim.x + threadIdx.x;
    if (i < NCL*SS) f[i] = 0;
}

__global__ __launch_bounds__(NT,2) void rnn_cluster(
    const int*   __restrict__ x,      // (B,S) in {-1,+1}
    const float* __restrict__ Wih0,   // (768,2)
    const float* __restrict__ Whh0,   // (768,256)
    const float* __restrict__ Wih1,   // (768,256)
    const float* __restrict__ Whh1,   // (768,256)
    const float* __restrict__ Wl,     // (2,256)
    const float* __restrict__ bl,     // (2,)
    float*       __restrict__ out,    // (B,)
    int*         __restrict__ flags,  // (NCL, SS) zeroed per launch
    _Float16*    __restrict__ Hbuf)   // 2 layers x NCL x 2 bufs x 128x256 halfs
{
    __shared__ _Float16 wlds[3*6*8*64*8];          // 147456 B
    __shared__ unsigned long long bitsM[BTC];

    const int t   = threadIdx.x;
    const int c   = blockIdx.x & (NCL-1);
    const int j   = blockIdx.x >> 5;               // member 0..7
    const int L   = t & 63;
    const int w   = t >> 6;
    const int lm  = L & 15, quad = L >> 4;
    const int mp  = w >> 1, hv = w & 1;

    _Float16* H0 = Hbuf + (size_t)c*(2*BTC*HH);
    _Float16* H1 = Hbuf + (size_t)(NCL + c)*(2*BTC*HH);
    int* flg = flags + c*SS;

    // ---- pack weight slice into LDS (once) ----
    for (int idx = t; idx < 3*6*8*64; idx += NT){
        int lane = idx & 63;
        int kt   = (idx >> 6) & 7;
        int ntl  = (idx >> 9) % 6;
        int mat  = idx / 3072;
        const float* W = (mat==0) ? Whh0 : (mat==1) ? Wih1 : Whh1;
        int g  = (ntl>>1)*HH + j*32 + (ntl&1)*16 + (lane & 15);
        int kb = kt*32 + (lane>>4)*8;
        _Float16* d = wlds + (size_t)idx*8;
        #pragma unroll
        for (int e=0;e<8;++e) d[e] = (_Float16)W[g*HH + kb + e];
    }
    if (t < BTC){
        unsigned long long m = 0;
        const int* xr = x + (size_t)(c*BTC + t)*SS;
        for (int s=0;s<SS;++s) if (xr[s] > 0) m |= (1ull<<s);
        bitsM[t] = m;
    }

    float g0w[6];
    { int ug = j*32 + hv*16 + lm;
      g0w[0]=Wih0[ug*2+0];        g0w[1]=Wih0[ug*2+1];
      g0w[2]=Wih0[(ug+HH)*2+0];   g0w[3]=Wih0[(ug+HH)*2+1];
      g0w[4]=Wih0[(ug+2*HH)*2+0]; g0w[5]=Wih0[(ug+2*HH)*2+1]; }

    const int srow = j*16 + (t>>5);
    const int cs   = t & 31;
    float wl0[8], wl1[8];
    #pragma unroll
    for (int e=0;e<8;++e){ wl0[e]=Wl[cs*8+e]; wl1[e]=Wl[HH+cs*8+e]; }
    const float bl0=bl[0], bl1=bl[1];

    float hr0[2][4] = {}, hr1[2][4] = {};
    float amp=1.f, ph=0.f, nup=0.f, ndn=0.f;

    __syncthreads();

    // ---- interval 0: h0n(0)=h1n(0)=0 exactly (zero input, no bias) ----
    {
        _Float16* wp1 = H1 + (32*mp + 4*quad)*HH + (j*32 + hv*16 + lm);
        #pragma unroll
        for (int m2=0;m2<2;++m2){
            #pragma unroll
            for (int reg=0;reg<4;++reg) wp1[(16*m2+reg)*HH] = (_Float16)0.f;
        }
        _Float16* wp0 = H0 + (BTC*HH) + (32*mp + 4*quad)*HH + (j*32 + hv*16 + lm);
        #pragma unroll
        for (int m2=0;m2<2;++m2){
            #pragma unroll
            for (int reg=0;reg<4;++reg){
                int rowL = 32*mp + 16*m2 + 4*quad + reg;
                int bit = (int)(bitsM[rowL] & 1ull);
                float gr = bit?g0w[1]:g0w[0];
                float gz = bit?g0w[3]:g0w[2];
                float gn = bit?g0w[5]:g0w[4];
                float r = sigmoidf_(gr);           // gh0 = 0
                float z = sigmoidf_(gz);
                float n = tanhf(gn);               // + r*0
                float hnew = (1.f-z)*n;            // + z*0
                hr0[m2][reg] = hnew;
                wp0[(16*m2+reg)*HH] = (_Float16)hnew;
            }
        }
    }
    __syncthreads();   // stores drained (vmcnt) for whole WG
    if (t==0){ __threadfence();
        __hip_atomic_fetch_add(&flg[0],1,__ATOMIC_RELAXED,__HIP_MEMORY_SCOPE_AGENT); }

    for (int i=1;i<SS;++i){
        // ---- wait bar(i-1): publishes h0n(i), h1n(i-1) ----
        if (t==0){
            int guard=0;
            while(__hip_atomic_load(&flg[i-1],__ATOMIC_RELAXED,__HIP_MEMORY_SCOPE_AGENT) < CW){
                __builtin_amdgcn_s_sleep(1);
                if (++guard > (1<<20)) break;   // safety: never hang the harness
            }
            __threadfence();
        }
        __syncthreads();

        // ---- sampling for step s = i-1 (h1n(s) published; hides under A-loads) ----
        {
            const int s = i-1;
            const _Float16* Hn = H1 + (s&1)*(BTC*HH) + srow*HH;
            half8 hvv = *(const half8*)(Hn + cs*8);
            float s0=0.f, s1=0.f;
            #pragma unroll
            for (int e=0;e<8;++e){ float f=(float)hvv[e]; s0+=f*wl0[e]; s1+=f*wl1[e]; }
            #pragma unroll
            for (int off=16; off>0; off>>=1){ s0+=__shfl_xor(s0,off,32); s1+=__shfl_xor(s1,off,32); }
            float l0=s0+bl0, l1=s1+bl1;
            bool  ev  = (s & 1) == 0;
            float low = -16.f + (float)(s>>1);
            float cnt = ev ? nup : ndn;
            float mocc = (16.f > cnt) ? 1.f : 0.f;
            float mun  = (low  < cnt) ? 1.f : 0.f;
            float mx = fmaxf(l0,l1);
            float e0 = expf(l0-mx), e1 = expf(l1-mx);
            float inv = 1.f/(e0+e1);
            float a0s = sqrtf(e0*inv)*mun;
            float a1s = sqrtf(e1*inv)*mocc;
            float nrm = sqrtf(a0s*a0s + a1s*a1s);
            float den = fmaxf(nrm, 1e-12f);
            a0s/=den; a1s/=den;
            const float PI_F = 3.14159265358979323846f;
            float p0 = PI_F*l0/(1.f+fabsf(l0));
            float p1 = PI_F*l1/(1.f+fabsf(l1));
            int bit = (int)((bitsM[srow] >> s) & 1ull);
            amp *= bit ? a1s : a0s;
            ph  += bit ? p1 : p0;
            if (ev) nup += (float)bit; else ndn += (float)bit;
        }

        // ---- fused GEMM phase: gh0(i+1), gi1(i) from A0=h0n(i); gh1(i) from A1=h1n(i-1) ----
        const _Float16* Hs0 = H0 + (i&1)*(BTC*HH)     + (32*mp + lm)*HH;
        const _Float16* Hs1 = H1 + ((i-1)&1)*(BTC*HH) + (32*mp + lm)*HH;
        f32x4 a0n[3][2] = {};
        f32x4 aR[2]={}, aZ[2]={}, aNI[2]={}, aNH[2]={};
        #pragma unroll
        for (int kh=0; kh<2; ++kh){            // two 4-kt chunks (VGPR pressure)
            half8 A0[4][2], A1[4][2];
            #pragma unroll
            for (int k2=0;k2<4;++k2){
                int kt = kh*4 + k2;
                A0[k2][0] = *(const half8*)(Hs0 +         kt*32 + quad*8);
                A0[k2][1] = *(const half8*)(Hs0 + 16*HH + kt*32 + quad*8);
                A1[k2][0] = *(const half8*)(Hs1 +         kt*32 + quad*8);
                A1[k2][1] = *(const half8*)(Hs1 + 16*HH + kt*32 + quad*8);
            }
            #pragma unroll
            for (int k2=0;k2<4;++k2){
                int kt = kh*4 + k2;
                half8 b0r = *(const half8*)(wlds + WOFF(0, 0+hv, kt) + L*8);
                half8 b0z = *(const half8*)(wlds + WOFF(0, 2+hv, kt) + L*8);
                half8 b0n = *(const half8*)(wlds + WOFF(0, 4+hv, kt) + L*8);
                half8 b1r = *(const half8*)(wlds + WOFF(1, 0+hv, kt) + L*8);
                half8 b1z = *(const half8*)(wlds + WOFF(1, 2+hv, kt) + L*8);
                half8 b1n = *(const half8*)(wlds + WOFF(1, 4+hv, kt) + L*8);
                half8 b2r = *(const half8*)(wlds + WOFF(2, 0+hv, kt) + L*8);
                half8 b2z = *(const half8*)(wlds + WOFF(2, 2+hv, kt) + L*8);
                half8 b2n = *(const half8*)(wlds + WOFF(2, 4+hv, kt) + L*8);
                #pragma unroll
                for (int m2=0;m2<2;++m2){
                    a0n[0][m2] = __builtin_amdgcn_mfma_f32_16x16x32_f16(A0[k2][m2], b0r, a0n[0][m2],0,0,0);
                    a0n[1][m2] = __builtin_amdgcn_mfma_f32_16x16x32_f16(A0[k2][m2], b0z, a0n[1][m2],0,0,0);
                    a0n[2][m2] = __builtin_amdgcn_mfma_f32_16x16x32_f16(A0[k2][m2], b0n, a0n[2][m2],0,0,0);
                    aR [m2]    = __builtin_amdgcn_mfma_f32_16x16x32_f16(A0[k2][m2], b1r, aR [m2],0,0,0);
                    aZ [m2]    = __builtin_amdgcn_mfma_f32_16x16x32_f16(A0[k2][m2], b1z, aZ [m2],0,0,0);
                    aNI[m2]    = __builtin_amdgcn_mfma_f32_16x16x32_f16(A0[k2][m2], b1n, aNI[m2],0,0,0);
                    aR [m2]    = __builtin_amdgcn_mfma_f32_16x16x32_f16(A1[k2][m2], b2r, aR [m2],0,0,0);
                    aZ [m2]    = __builtin_amdgcn_mfma_f32_16x16x32_f16(A1[k2][m2], b2z, aZ [m2],0,0,0);
                    aNH[m2]    = __builtin_amdgcn_mfma_f32_16x16x32_f16(A1[k2][m2], b2n, aNH[m2],0,0,0);
                }
            }
        }

        // ---- ew1(i): h1n(i) -> H1[i&1] ----
        {
            _Float16* wp = H1 + (i&1)*(BTC*HH) + (32*mp + 4*quad)*HH + (j*32 + hv*16 + lm);
            #pragma unroll
            for (int m2=0;m2<2;++m2){
                #pragma unroll
                for (int reg=0;reg<4;++reg){
                    float r = sigmoidf_(aR[m2][reg]);
                    float z = sigmoidf_(aZ[m2][reg]);
                    float n = tanhf(aNI[m2][reg] + r*aNH[m2][reg]);
                    float hnew = (1.f-z)*n + z*hr1[m2][reg];
                    hr1[m2][reg] = hnew;
                    wp[(16*m2 + reg)*HH] = (_Float16)hnew;
                }
            }
        }

        // ---- ew0(i+1): h0n(i+1) -> H0[(i+1)&1] (skip useless last one) ----
        if (i < SS-1){
            _Float16* wp = H0 + ((i+1)&1)*(BTC*HH) + (32*mp + 4*quad)*HH + (j*32 + hv*16 + lm);
            #pragma unroll
            for (int m2=0;m2<2;++m2){
                #pragma unroll
                for (int reg=0;reg<4;++reg){
                    int rowL = 32*mp + 16*m2 + 4*quad + reg;
                    int bit = (int)((bitsM[rowL] >> i) & 1ull);
                    float gr = bit?g0w[1]:g0w[0];
                    float gz = bit?g0w[3]:g0w[2];
                    float gn = bit?g0w[5]:g0w[4];
                    float r = sigmoidf_(gr + a0n[0][m2][reg]);
                    float z = sigmoidf_(gz + a0n[1][m2][reg]);
                    float n = tanhf(gn + r*a0n[2][m2][reg]);
                    float hnew = (1.f-z)*n + z*hr0[m2][reg];
                    hr0[m2][reg] = hnew;
                    wp[(16*m2 + reg)*HH] = (_Float16)hnew;
                }
            }
        }

        // ---- arrive bar(i): publishes h1n(i), h0n(i+1) ----
        __syncthreads();
        if (t==0){ __threadfence();
            __hip_atomic_fetch_add(&flg[i],1,__ATOMIC_RELAXED,__HIP_MEMORY_SCOPE_AGENT); }
    }

    // ---- epilogue: wait bar(63), sampling(63) ----
    if (t==0){
        int guard=0;
        while(__hip_atomic_load(&flg[SS-1],__ATOMIC_RELAXED,__HIP_MEMORY_SCOPE_AGENT) < CW){
            __builtin_amdgcn_s_sleep(1);
            if (++guard > (1<<20)) break;
        }
        __threadfence();
    }
    __syncthreads();
    {
        const int s = SS-1;
        const _Float16* Hn = H1 + (s&1)*(BTC*HH) + srow*HH;
        half8 hvv = *(const half8*)(Hn + cs*8);
        float s0=0.f, s1=0.f;
        #pragma unroll
        for (int e=0;e<8;++e){ float f=(float)hvv[e]; s0+=f*wl0[e]; s1+=f*wl1[e]; }
        #pragma unroll
        for (int off=16; off>0; off>>=1){ s0+=__shfl_xor(s0,off,32); s1+=__shfl_xor(s1,off,32); }
        float l0=s0+bl0, l1=s1+bl1;
        bool  ev  = (s & 1) == 0;
        float low = -16.f + (float)(s>>1);
        float cnt = ev ? nup : ndn;
        float mocc = (16.f > cnt) ? 1.f : 0.f;
        float mun  = (low  < cnt) ? 1.f : 0.f;
        float mx = fmaxf(l0,l1);
        float e0 = expf(l0-mx), e1 = expf(l1-mx);
        float inv = 1.f/(e0+e1);
        float a0s = sqrtf(e0*inv)*mun;
        float a1s = sqrtf(e1*inv)*mocc;
        float nrm = sqrtf(a0s*a0s + a1s*a1s);
        float den = fmaxf(nrm, 1e-12f);
        a0s/=den; a1s/=den;
        const float PI_F = 3.14159265358979323846f;
        float p0 = PI_F*l0/(1.f+fabsf(l0));
        float p1 = PI_F*l1/(1.f+fabsf(l1));
        int bit = (int)((bitsM[srow] >> s) & 1ull);
        amp *= bit ? a1s : a0s;
        ph  += bit ? p1 : p0;
    }
    if (cs == 0) out[c*BTC + srow] = amp * cosf(ph);
}

extern "C" void kernel_launch(void* const* d_in, const int* in_sizes, int n_in,
                              void* d_out, int out_size, void* d_ws, size_t ws_size,
                              hipStream_t stream) {
    (void)in_sizes; (void)n_in; (void)out_size; (void)ws_size;
    const int*   x    = (const int*)d_in[0];
    const float* Wih0 = (const float*)d_in[1];
    const float* Whh0 = (const float*)d_in[2];
    const float* Wih1 = (const float*)d_in[3];
    const float* Whh1 = (const float*)d_in[4];
    const float* Wl   = (const float*)d_in[5];
    const float* bl   = (const float*)d_in[6];

    int*      flags = (int*)d_ws;                         // 8 KB used, 64 KB reserved
    _Float16* Hbuf  = (_Float16*)((char*)d_ws + 65536);   // 8 MB h state

    zero_flags<<<(NCL*SS + 255)/256, 256, 0, stream>>>(flags);
    rnn_cluster<<<NCL*CW, NT, 0, stream>>>(x, Wih0, Whh0, Wih1, Whh1, Wl, bl,
                                           (float*)d_out, flags, Hbuf);
}

// Round 3
// 1239.940 us; speedup vs baseline: 2.1554x; 1.1833x over previous
//
#include <hip/hip_runtime.h>
#include <math.h>

// B=4096, S=64, H=256, 2 GRU layers.
// 32 clusters x 8 WGs (=256 WGs, 1/CU). Weight slice (144 KB fp16) LDS-resident.
// Pipelined: ONE cluster barrier + ONE fused {A-load -> 3 GEMMs} phase per step.
// h-state exchanged through the Infinity Cache (device coherence point):
//   stores = global_store_short sc0 sc1 (write-through, no dirty L2),
//   loads  = agent-scope relaxed atomic loads (bypass stale L1/L2).
// -> NO threadfence / buffer_wbl2 / buffer_inv in the main loop.
#define NCL 32
#define CW  8
#define BTC 128
#define NT  512
#define SS  64
#define HH  256

typedef __attribute__((ext_vector_type(8))) _Float16 half8;
typedef __attribute__((ext_vector_type(4))) float    f32x4;

__device__ __forceinline__ float sigmoidf_(float v){ return 1.0f/(1.0f+expf(-v)); }

// h load: 16B via two agent-scope relaxed u64 atomic loads (L1/L2 bypass -> IC)
__device__ __forceinline__ half8 ldA(const _Float16* p){
    union { unsigned long long u[2]; half8 h; } r;
    const unsigned long long* q = (const unsigned long long*)p;
    r.u[0] = __hip_atomic_load(q,   __ATOMIC_RELAXED, __HIP_MEMORY_SCOPE_AGENT);
    r.u[1] = __hip_atomic_load(q+1, __ATOMIC_RELAXED, __HIP_MEMORY_SCOPE_AGENT);
    return r.h;
}
// h store: 2B write-through to IC (sc0 sc1) — leaves no dirty L2 line
__device__ __forceinline__ void stH(_Float16* p, float v){
    _Float16 hv = (_Float16)v;
    asm volatile("global_store_short %0, %1, off sc0 sc1" :: "v"(p), "v"(hv));
}

// LDS weight layout: halfs offset = mat*24576 + ntl*4096 + kt*512 + lane*8
// mat: 0=Whh0 1=Wih1 2=Whh1 ; ntl = type*2 + hv (type 0=r,1=z,2=n)
#define WOFF(mat,ntl,kt) ((mat)*24576 + (ntl)*4096 + (kt)*512)

__global__ void zero_flags(int* f){
    int i = blockIdx.x*blockDim.x + threadIdx.x;
    if (i < NCL*SS) f[i] = 0;
}

__global__ __launch_bounds__(NT,2) void rnn_cluster(
    const int*   __restrict__ x,
    const float* __restrict__ Wih0,
    const float* __restrict__ Whh0,
    const float* __restrict__ Wih1,
    const float* __restrict__ Whh1,
    const float* __restrict__ Wl,
    const float* __restrict__ bl,
    float*       __restrict__ out,
    int*         __restrict__ flags,  // (NCL, SS) zeroed per launch
    _Float16*    __restrict__ Hbuf)   // 2 layers x NCL x 2 bufs x 128x256 halfs
{
    __shared__ _Float16 wlds[3*6*8*64*8];          // 147456 B
    __shared__ unsigned long long bitsM[BTC];

    const int t   = threadIdx.x;
    const int c   = blockIdx.x & (NCL-1);
    const int j   = blockIdx.x >> 5;               // member 0..7
    const int L   = t & 63;
    const int w   = t >> 6;
    const int lm  = L & 15, quad = L >> 4;
    const int mp  = w >> 1, hv = w & 1;

    _Float16* H0 = Hbuf + (size_t)c*(2*BTC*HH);
    _Float16* H1 = Hbuf + (size_t)(NCL + c)*(2*BTC*HH);
    int* flg = flags + c*SS;

    // ---- pack weight slice into LDS (once) ----
    for (int idx = t; idx < 3*6*8*64; idx += NT){
        int lane = idx & 63;
        int kt   = (idx >> 6) & 7;
        int ntl  = (idx >> 9) % 6;
        int mat  = idx / 3072;
        const float* W = (mat==0) ? Whh0 : (mat==1) ? Wih1 : Whh1;
        int g  = (ntl>>1)*HH + j*32 + (ntl&1)*16 + (lane & 15);
        int kb = kt*32 + (lane>>4)*8;
        _Float16* d = wlds + (size_t)idx*8;
        #pragma unroll
        for (int e=0;e<8;++e) d[e] = (_Float16)W[g*HH + kb + e];
    }
    if (t < BTC){
        unsigned long long m = 0;
        const int* xr = x + (size_t)(c*BTC + t)*SS;
        for (int s=0;s<SS;++s) if (xr[s] > 0) m |= (1ull<<s);
        bitsM[t] = m;
    }

    float g0w[6];
    { int ug = j*32 + hv*16 + lm;
      g0w[0]=Wih0[ug*2+0];        g0w[1]=Wih0[ug*2+1];
      g0w[2]=Wih0[(ug+HH)*2+0];   g0w[3]=Wih0[(ug+HH)*2+1];
      g0w[4]=Wih0[(ug+2*HH)*2+0]; g0w[5]=Wih0[(ug+2*HH)*2+1]; }

    const int srow = j*16 + (t>>5);
    const int cs   = t & 31;
    float wl0[8], wl1[8];
    #pragma unroll
    for (int e=0;e<8;++e){ wl0[e]=Wl[cs*8+e]; wl1[e]=Wl[HH+cs*8+e]; }
    const float bl0=bl[0], bl1=bl[1];

    float hr0[2][4] = {}, hr1[2][4] = {};
    float amp=1.f, ph=0.f, nup=0.f, ndn=0.f;

    __syncthreads();

    // ---- interval 0: h0n(0)=h1n(0)=0 exactly (zero input, no bias) ----
    {
        _Float16* wp1 = H1 + (32*mp + 4*quad)*HH + (j*32 + hv*16 + lm);
        #pragma unroll
        for (int m2=0;m2<2;++m2){
            #pragma unroll
            for (int reg=0;reg<4;++reg) stH(wp1 + (16*m2+reg)*HH, 0.f);
        }
        _Float16* wp0 = H0 + (BTC*HH) + (32*mp + 4*quad)*HH + (j*32 + hv*16 + lm);
        #pragma unroll
        for (int m2=0;m2<2;++m2){
            #pragma unroll
            for (int reg=0;reg<4;++reg){
                int rowL = 32*mp + 16*m2 + 4*quad + reg;
                int bit = (int)(bitsM[rowL] & 1ull);
                float gr = bit?g0w[1]:g0w[0];
                float gz = bit?g0w[3]:g0w[2];
                float gn = bit?g0w[5]:g0w[4];
                float r = sigmoidf_(gr);
                float z = sigmoidf_(gz);
                float n = tanhf(gn);
                float hnew = (1.f-z)*n;
                hr0[m2][reg] = hnew;
                stH(wp0 + (16*m2+reg)*HH, hnew);
            }
        }
    }
    asm volatile("s_waitcnt vmcnt(0)" ::: "memory");   // drain write-throughs to IC
    __syncthreads();
    if (t==0)
        __hip_atomic_fetch_add(&flg[0],1,__ATOMIC_RELAXED,__HIP_MEMORY_SCOPE_AGENT);

    for (int i=1;i<SS;++i){
        // ---- wait bar(i-1): publishes h0n(i), h1n(i-1) ----
        if (t==0){
            int guard=0;
            while(__hip_atomic_load(&flg[i-1],__ATOMIC_RELAXED,__HIP_MEMORY_SCOPE_AGENT) < CW){
                __builtin_amdgcn_s_sleep(1);
                if (++guard > (1<<20)) break;   // safety: never hang the harness
            }
        }
        __syncthreads();

        const int s = i-1;
        const _Float16* Hn  = H1 + (s&1)*(BTC*HH) + srow*HH + cs*8;
        const _Float16* Hs0 = H0 + (i&1)*(BTC*HH)     + (32*mp + lm)*HH;
        const _Float16* Hs1 = H1 + ((i-1)&1)*(BTC*HH) + (32*mp + lm)*HH;

        // issue sampling load first (latency hidden under A-loads/math)
        half8 hvv = ldA(Hn);

        f32x4 a0n[3][2] = {};
        f32x4 aR[2]={}, aZ[2]={}, aNI[2]={}, aNH[2]={};

        // ---- chunk kh=0: issue loads ----
        half8 A0a[4][2], A1a[4][2];
        #pragma unroll
        for (int k2=0;k2<4;++k2){
            A0a[k2][0] = ldA(Hs0 +         k2*32 + quad*8);
            A0a[k2][1] = ldA(Hs0 + 16*HH + k2*32 + quad*8);
            A1a[k2][0] = ldA(Hs1 +         k2*32 + quad*8);
            A1a[k2][1] = ldA(Hs1 + 16*HH + k2*32 + quad*8);
        }

        // ---- sampling math for step s (overlaps A-load latency) ----
        {
            float s0=0.f, s1=0.f;
            #pragma unroll
            for (int e=0;e<8;++e){ float f=(float)hvv[e]; s0+=f*wl0[e]; s1+=f*wl1[e]; }
            #pragma unroll
            for (int off=16; off>0; off>>=1){ s0+=__shfl_xor(s0,off,32); s1+=__shfl_xor(s1,off,32); }
            float l0=s0+bl0, l1=s1+bl1;
            bool  ev  = (s & 1) == 0;
            float low = -16.f + (float)(s>>1);
            float cnt = ev ? nup : ndn;
            float mocc = (16.f > cnt) ? 1.f : 0.f;
            float mun  = (low  < cnt) ? 1.f : 0.f;
            float mx = fmaxf(l0,l1);
            float e0 = expf(l0-mx), e1 = expf(l1-mx);
            float inv = 1.f/(e0+e1);
            float a0s = sqrtf(e0*inv)*mun;
            float a1s = sqrtf(e1*inv)*mocc;
            float nrm = sqrtf(a0s*a0s + a1s*a1s);
            float den = fmaxf(nrm, 1e-12f);
            a0s/=den; a1s/=den;
            const float PI_F = 3.14159265358979323846f;
            float p0 = PI_F*l0/(1.f+fabsf(l0));
            float p1 = PI_F*l1/(1.f+fabsf(l1));
            int bit = (int)((bitsM[srow] >> s) & 1ull);
            amp *= bit ? a1s : a0s;
            ph  += bit ? p1 : p0;
            if (ev) nup += (float)bit; else ndn += (float)bit;
        }

        // ---- chunk kh=0: MFMAs ----
        #pragma unroll
        for (int k2=0;k2<4;++k2){
            int kt = k2;
            half8 b0r = *(const half8*)(wlds + WOFF(0, 0+hv, kt) + L*8);
            half8 b0z = *(const half8*)(wlds + WOFF(0, 2+hv, kt) + L*8);
            half8 b0n = *(const half8*)(wlds + WOFF(0, 4+hv, kt) + L*8);
            half8 b1r = *(const half8*)(wlds + WOFF(1, 0+hv, kt) + L*8);
            half8 b1z = *(const half8*)(wlds + WOFF(1, 2+hv, kt) + L*8);
            half8 b1n = *(const half8*)(wlds + WOFF(1, 4+hv, kt) + L*8);
            half8 b2r = *(const half8*)(wlds + WOFF(2, 0+hv, kt) + L*8);
            half8 b2z = *(const half8*)(wlds + WOFF(2, 2+hv, kt) + L*8);
            half8 b2n = *(const half8*)(wlds + WOFF(2, 4+hv, kt) + L*8);
            #pragma unroll
            for (int m2=0;m2<2;++m2){
                a0n[0][m2] = __builtin_amdgcn_mfma_f32_16x16x32_f16(A0a[k2][m2], b0r, a0n[0][m2],0,0,0);
                a0n[1][m2] = __builtin_amdgcn_mfma_f32_16x16x32_f16(A0a[k2][m2], b0z, a0n[1][m2],0,0,0);
                a0n[2][m2] = __builtin_amdgcn_mfma_f32_16x16x32_f16(A0a[k2][m2], b0n, a0n[2][m2],0,0,0);
                aR [m2]    = __builtin_amdgcn_mfma_f32_16x16x32_f16(A0a[k2][m2], b1r, aR [m2],0,0,0);
                aZ [m2]    = __builtin_amdgcn_mfma_f32_16x16x32_f16(A0a[k2][m2], b1z, aZ [m2],0,0,0);
                aNI[m2]    = __builtin_amdgcn_mfma_f32_16x16x32_f16(A0a[k2][m2], b1n, aNI[m2],0,0,0);
                aR [m2]    = __builtin_amdgcn_mfma_f32_16x16x32_f16(A1a[k2][m2], b2r, aR [m2],0,0,0);
                aZ [m2]    = __builtin_amdgcn_mfma_f32_16x16x32_f16(A1a[k2][m2], b2z, aZ [m2],0,0,0);
                aNH[m2]    = __builtin_amdgcn_mfma_f32_16x16x32_f16(A1a[k2][m2], b2n, aNH[m2],0,0,0);
            }
        }

        // ---- chunk kh=1: loads then MFMAs ----
        half8 A0b[4][2], A1b[4][2];
        #pragma unroll
        for (int k2=0;k2<4;++k2){
            int kt = 4+k2;
            A0b[k2][0] = ldA(Hs0 +         kt*32 + quad*8);
            A0b[k2][1] = ldA(Hs0 + 16*HH + kt*32 + quad*8);
            A1b[k2][0] = ldA(Hs1 +         kt*32 + quad*8);
            A1b[k2][1] = ldA(Hs1 + 16*HH + kt*32 + quad*8);
        }
        #pragma unroll
        for (int k2=0;k2<4;++k2){
            int kt = 4+k2;
            half8 b0r = *(const half8*)(wlds + WOFF(0, 0+hv, kt) + L*8);
            half8 b0z = *(const half8*)(wlds + WOFF(0, 2+hv, kt) + L*8);
            half8 b0n = *(const half8*)(wlds + WOFF(0, 4+hv, kt) + L*8);
            half8 b1r = *(const half8*)(wlds + WOFF(1, 0+hv, kt) + L*8);
            half8 b1z = *(const half8*)(wlds + WOFF(1, 2+hv, kt) + L*8);
            half8 b1n = *(const half8*)(wlds + WOFF(1, 4+hv, kt) + L*8);
            half8 b2r = *(const half8*)(wlds + WOFF(2, 0+hv, kt) + L*8);
            half8 b2z = *(const half8*)(wlds + WOFF(2, 2+hv, kt) + L*8);
            half8 b2n = *(const half8*)(wlds + WOFF(2, 4+hv, kt) + L*8);
            #pragma unroll
            for (int m2=0;m2<2;++m2){
                a0n[0][m2] = __builtin_amdgcn_mfma_f32_16x16x32_f16(A0b[k2][m2], b0r, a0n[0][m2],0,0,0);
                a0n[1][m2] = __builtin_amdgcn_mfma_f32_16x16x32_f16(A0b[k2][m2], b0z, a0n[1][m2],0,0,0);
                a0n[2][m2] = __builtin_amdgcn_mfma_f32_16x16x32_f16(A0b[k2][m2], b0n, a0n[2][m2],0,0,0);
                aR [m2]    = __builtin_amdgcn_mfma_f32_16x16x32_f16(A0b[k2][m2], b1r, aR [m2],0,0,0);
                aZ [m2]    = __builtin_amdgcn_mfma_f32_16x16x32_f16(A0b[k2][m2], b1z, aZ [m2],0,0,0);
                aNI[m2]    = __builtin_amdgcn_mfma_f32_16x16x32_f16(A0b[k2][m2], b1n, aNI[m2],0,0,0);
                aR [m2]    = __builtin_amdgcn_mfma_f32_16x16x32_f16(A1b[k2][m2], b2r, aR [m2],0,0,0);
                aZ [m2]    = __builtin_amdgcn_mfma_f32_16x16x32_f16(A1b[k2][m2], b2z, aZ [m2],0,0,0);
                aNH[m2]    = __builtin_amdgcn_mfma_f32_16x16x32_f16(A1b[k2][m2], b2n, aNH[m2],0,0,0);
            }
        }

        // ---- ew1(i): h1n(i) -> H1[i&1] ----
        {
            _Float16* wp = H1 + (i&1)*(BTC*HH) + (32*mp + 4*quad)*HH + (j*32 + hv*16 + lm);
            #pragma unroll
            for (int m2=0;m2<2;++m2){
                #pragma unroll
                for (int reg=0;reg<4;++reg){
                    float r = sigmoidf_(aR[m2][reg]);
                    float z = sigmoidf_(aZ[m2][reg]);
                    float n = tanhf(aNI[m2][reg] + r*aNH[m2][reg]);
                    float hnew = (1.f-z)*n + z*hr1[m2][reg];
                    hr1[m2][reg] = hnew;
                    stH(wp + (16*m2 + reg)*HH, hnew);
                }
            }
        }

        // ---- ew0(i+1): h0n(i+1) -> H0[(i+1)&1] (skip useless last one) ----
        if (i < SS-1){
            _Float16* wp = H0 + ((i+1)&1)*(BTC*HH) + (32*mp + 4*quad)*HH + (j*32 + hv*16 + lm);
            #pragma unroll
            for (int m2=0;m2<2;++m2){
                #pragma unroll
                for (int reg=0;reg<4;++reg){
                    int rowL = 32*mp + 16*m2 + 4*quad + reg;
                    int bit = (int)((bitsM[rowL] >> i) & 1ull);
                    float gr = bit?g0w[1]:g0w[0];
                    float gz = bit?g0w[3]:g0w[2];
                    float gn = bit?g0w[5]:g0w[4];
                    float r = sigmoidf_(gr + a0n[0][m2][reg]);
                    float z = sigmoidf_(gz + a0n[1][m2][reg]);
                    float n = tanhf(gn + r*a0n[2][m2][reg]);
                    float hnew = (1.f-z)*n + z*hr0[m2][reg];
                    hr0[m2][reg] = hnew;
                    stH(wp + (16*m2 + reg)*HH, hnew);
                }
            }
        }

        // ---- arrive bar(i): publishes h1n(i), h0n(i+1) ----
        asm volatile("s_waitcnt vmcnt(0)" ::: "memory");   // write-throughs at IC
        __syncthreads();
        if (t==0)
            __hip_atomic_fetch_add(&flg[i],1,__ATOMIC_RELAXED,__HIP_MEMORY_SCOPE_AGENT);
    }

    // ---- epilogue: wait bar(63), sampling(63) ----
    if (t==0){
        int guard=0;
        while(__hip_atomic_load(&flg[SS-1],__ATOMIC_RELAXED,__HIP_MEMORY_SCOPE_AGENT) < CW){
            __builtin_amdgcn_s_sleep(1);
            if (++guard > (1<<20)) break;
        }
    }
    __syncthreads();
    {
        const int s = SS-1;
        const _Float16* Hn = H1 + (s&1)*(BTC*HH) + srow*HH + cs*8;
        half8 hvv = ldA(Hn);
        float s0=0.f, s1=0.f;
        #pragma unroll
        for (int e=0;e<8;++e){ float f=(float)hvv[e]; s0+=f*wl0[e]; s1+=f*wl1[e]; }
        #pragma unroll
        for (int off=16; off>0; off>>=1){ s0+=__shfl_xor(s0,off,32); s1+=__shfl_xor(s1,off,32); }
        float l0=s0+bl0, l1=s1+bl1;
        bool  ev  = (s & 1) == 0;
        float low = -16.f + (float)(s>>1);
        float cnt = ev ? nup : ndn;
        float mocc = (16.f > cnt) ? 1.f : 0.f;
        float mun  = (low  < cnt) ? 1.f : 0.f;
        float mx = fmaxf(l0,l1);
        float e0 = expf(l0-mx), e1 = expf(l1-mx);
        float inv = 1.f/(e0+e1);
        float a0s = sqrtf(e0*inv)*mun;
        float a1s = sqrtf(e1*inv)*mocc;
        float nrm = sqrtf(a0s*a0s + a1s*a1s);
        float den = fmaxf(nrm, 1e-12f);
        a0s/=den; a1s/=den;
        const float PI_F = 3.14159265358979323846f;
        float p0 = PI_F*l0/(1.f+fabsf(l0));
        float p1 = PI_F*l1/(1.f+fabsf(l1));
        int bit = (int)((bitsM[srow] >> s) & 1ull);
        amp *= bit ? a1s : a0s;
        ph  += bit ? p1 : p0;
    }
    if (cs == 0) out[c*BTC + srow] = amp * cosf(ph);
}

extern "C" void kernel_launch(void* const* d_in, const int* in_sizes, int n_in,
                              void* d_out, int out_size, void* d_ws, size_t ws_size,
                              hipStream_t stream) {
    (void)in_sizes; (void)n_in; (void)out_size; (void)ws_size;
    const int*   x    = (const int*)d_in[0];
    const float* Wih0 = (const float*)d_in[1];
    const float* Whh0 = (const float*)d_in[2];
    const float* Wih1 = (const float*)d_in[3];
    const float* Whh1 = (const float*)d_in[4];
    const float* Wl   = (const float*)d_in[5];
    const float* bl   = (const float*)d_in[6];

    int*      flags = (int*)d_ws;                         // 8 KB used, 64 KB reserved
    _Float16* Hbuf  = (_Float16*)((char*)d_ws + 65536);   // 8 MB h state

    zero_flags<<<(NCL*SS + 255)/256, 256, 0, stream>>>(flags);
    rnn_cluster<<<NCL*CW, NT, 0, stream>>>(x, Wih0, Whh0, Wih1, Whh1, Wl, bl,
                                           (float*)d_out, flags, Hbuf);
}

// Round 4
// 1130.693 us; speedup vs baseline: 2.3637x; 1.0966x over previous
//
#include <hip/hip_runtime.h>
#include <math.h>

// B=4096, S=64, H=256, 2 GRU layers.
// 32 clusters x 8 WGs (=256 WGs, 1/CU). Weight slice (144 KB fp16) LDS-resident.
// Pipelined: ONE cluster barrier + ONE fused {A-load -> 3 GEMMs} phase per step.
// h-state exchanged through the Infinity Cache (device coherence point):
//   stores = global_store_short sc0 sc1 (write-through, no dirty L2),
//   loads  = agent-scope relaxed atomic loads (bypass stale L1/L2).
// This round: native-HW transcendentals (v_exp/v_rcp/v_sqrt) replace OCML
// precise expf/tanhf — the measured constant ~5.4 us/step VALU wall.
#define NCL 32
#define CW  8
#define BTC 128
#define NT  512
#define SS  64
#define HH  256

typedef __attribute__((ext_vector_type(8))) _Float16 half8;
typedef __attribute__((ext_vector_type(4))) float    f32x4;

// native fast transcendentals (hot path): ~1-3 ulp, fp16-h noise dominates
__device__ __forceinline__ float sigmoidf_(float v){
    return __builtin_amdgcn_rcpf(1.f + __expf(-v));
}
__device__ __forceinline__ float tanhf_(float x){
    // tanh(x) = 1 - 2/(e^{2x}+1); saturates correctly for |x| large
    return 1.f - 2.f*__builtin_amdgcn_rcpf(1.f + __expf(2.f*x));
}

// h load: 16B via two agent-scope relaxed u64 atomic loads (L1/L2 bypass -> IC)
__device__ __forceinline__ half8 ldA(const _Float16* p){
    union { unsigned long long u[2]; half8 h; } r;
    const unsigned long long* q = (const unsigned long long*)p;
    r.u[0] = __hip_atomic_load(q,   __ATOMIC_RELAXED, __HIP_MEMORY_SCOPE_AGENT);
    r.u[1] = __hip_atomic_load(q+1, __ATOMIC_RELAXED, __HIP_MEMORY_SCOPE_AGENT);
    return r.h;
}
// h store: 2B write-through to IC (sc0 sc1) — leaves no dirty L2 line
__device__ __forceinline__ void stH(_Float16* p, float v){
    _Float16 hv = (_Float16)v;
    asm volatile("global_store_short %0, %1, off sc0 sc1" :: "v"(p), "v"(hv));
}

// LDS weight layout: halfs offset = mat*24576 + ntl*4096 + kt*512 + lane*8
// mat: 0=Whh0 1=Wih1 2=Whh1 ; ntl = type*2 + hv (type 0=r,1=z,2=n)
#define WOFF(mat,ntl,kt) ((mat)*24576 + (ntl)*4096 + (kt)*512)

__global__ void zero_flags(int* f){
    int i = blockIdx.x*blockDim.x + threadIdx.x;
    if (i < NCL*SS) f[i] = 0;
}

__global__ __launch_bounds__(NT,2) void rnn_cluster(
    const int*   __restrict__ x,
    const float* __restrict__ Wih0,
    const float* __restrict__ Whh0,
    const float* __restrict__ Wih1,
    const float* __restrict__ Whh1,
    const float* __restrict__ Wl,
    const float* __restrict__ bl,
    float*       __restrict__ out,
    int*         __restrict__ flags,  // (NCL, SS) zeroed per launch
    _Float16*    __restrict__ Hbuf)   // 2 layers x NCL x 2 bufs x 128x256 halfs
{
    __shared__ _Float16 wlds[3*6*8*64*8];          // 147456 B
    __shared__ unsigned long long bitsM[BTC];

    const int t   = threadIdx.x;
    const int c   = blockIdx.x & (NCL-1);
    const int j   = blockIdx.x >> 5;               // member 0..7
    const int L   = t & 63;
    const int w   = t >> 6;
    const int lm  = L & 15, quad = L >> 4;
    const int mp  = w >> 1, hv = w & 1;

    _Float16* H0 = Hbuf + (size_t)c*(2*BTC*HH);
    _Float16* H1 = Hbuf + (size_t)(NCL + c)*(2*BTC*HH);
    int* flg = flags + c*SS;

    // ---- pack weight slice into LDS (once) ----
    for (int idx = t; idx < 3*6*8*64; idx += NT){
        int lane = idx & 63;
        int kt   = (idx >> 6) & 7;
        int ntl  = (idx >> 9) % 6;
        int mat  = idx / 3072;
        const float* W = (mat==0) ? Whh0 : (mat==1) ? Wih1 : Whh1;
        int g  = (ntl>>1)*HH + j*32 + (ntl&1)*16 + (lane & 15);
        int kb = kt*32 + (lane>>4)*8;
        _Float16* d = wlds + (size_t)idx*8;
        #pragma unroll
        for (int e=0;e<8;++e) d[e] = (_Float16)W[g*HH + kb + e];
    }
    if (t < BTC){
        unsigned long long m = 0;
        const int* xr = x + (size_t)(c*BTC + t)*SS;
        for (int s=0;s<SS;++s) if (xr[s] > 0) m |= (1ull<<s);
        bitsM[t] = m;
    }

    float g0w[6];
    { int ug = j*32 + hv*16 + lm;
      g0w[0]=Wih0[ug*2+0];        g0w[1]=Wih0[ug*2+1];
      g0w[2]=Wih0[(ug+HH)*2+0];   g0w[3]=Wih0[(ug+HH)*2+1];
      g0w[4]=Wih0[(ug+2*HH)*2+0]; g0w[5]=Wih0[(ug+2*HH)*2+1]; }

    const int srow = j*16 + (t>>5);
    const int cs   = t & 31;
    float wl0[8], wl1[8];
    #pragma unroll
    for (int e=0;e<8;++e){ wl0[e]=Wl[cs*8+e]; wl1[e]=Wl[HH+cs*8+e]; }
    const float bl0=bl[0], bl1=bl[1];

    float hr0[2][4] = {}, hr1[2][4] = {};
    float amp=1.f, ph=0.f, nup=0.f, ndn=0.f;

    __syncthreads();

    // ---- interval 0: h0n(0)=h1n(0)=0 exactly (zero input, no bias) ----
    {
        _Float16* wp1 = H1 + (32*mp + 4*quad)*HH + (j*32 + hv*16 + lm);
        #pragma unroll
        for (int m2=0;m2<2;++m2){
            #pragma unroll
            for (int reg=0;reg<4;++reg) stH(wp1 + (16*m2+reg)*HH, 0.f);
        }
        _Float16* wp0 = H0 + (BTC*HH) + (32*mp + 4*quad)*HH + (j*32 + hv*16 + lm);
        #pragma unroll
        for (int m2=0;m2<2;++m2){
            #pragma unroll
            for (int reg=0;reg<4;++reg){
                int rowL = 32*mp + 16*m2 + 4*quad + reg;
                int bit = (int)(bitsM[rowL] & 1ull);
                float gr = bit?g0w[1]:g0w[0];
                float gz = bit?g0w[3]:g0w[2];
                float gn = bit?g0w[5]:g0w[4];
                float r = sigmoidf_(gr);
                float z = sigmoidf_(gz);
                float n = tanhf_(gn);
                float hnew = (1.f-z)*n;
                hr0[m2][reg] = hnew;
                stH(wp0 + (16*m2+reg)*HH, hnew);
            }
        }
    }
    asm volatile("s_waitcnt vmcnt(0)" ::: "memory");   // drain write-throughs to IC
    __syncthreads();
    if (t==0)
        __hip_atomic_fetch_add(&flg[0],1,__ATOMIC_RELAXED,__HIP_MEMORY_SCOPE_AGENT);

    for (int i=1;i<SS;++i){
        // ---- wait bar(i-1): publishes h0n(i), h1n(i-1) ----
        if (t==0){
            int guard=0;
            while(__hip_atomic_load(&flg[i-1],__ATOMIC_RELAXED,__HIP_MEMORY_SCOPE_AGENT) < CW){
                __builtin_amdgcn_s_sleep(1);
                if (++guard > (1<<20)) break;   // safety: never hang the harness
            }
        }
        __syncthreads();

        const int s = i-1;
        const _Float16* Hn  = H1 + (s&1)*(BTC*HH) + srow*HH + cs*8;
        const _Float16* Hs0 = H0 + (i&1)*(BTC*HH)     + (32*mp + lm)*HH;
        const _Float16* Hs1 = H1 + ((i-1)&1)*(BTC*HH) + (32*mp + lm)*HH;

        // issue sampling load first (latency hidden under A-loads/math)
        half8 hvv = ldA(Hn);

        f32x4 a0n[3][2] = {};
        f32x4 aR[2]={}, aZ[2]={}, aNI[2]={}, aNH[2]={};

        // ---- chunk kh=0: issue loads ----
        half8 A0a[4][2], A1a[4][2];
        #pragma unroll
        for (int k2=0;k2<4;++k2){
            A0a[k2][0] = ldA(Hs0 +         k2*32 + quad*8);
            A0a[k2][1] = ldA(Hs0 + 16*HH + k2*32 + quad*8);
            A1a[k2][0] = ldA(Hs1 +         k2*32 + quad*8);
            A1a[k2][1] = ldA(Hs1 + 16*HH + k2*32 + quad*8);
        }

        // ---- sampling math for step s (overlaps A-load latency) ----
        {
            float s0=0.f, s1=0.f;
            #pragma unroll
            for (int e=0;e<8;++e){ float f=(float)hvv[e]; s0+=f*wl0[e]; s1+=f*wl1[e]; }
            #pragma unroll
            for (int off=16; off>0; off>>=1){ s0+=__shfl_xor(s0,off,32); s1+=__shfl_xor(s1,off,32); }
            float l0=s0+bl0, l1=s1+bl1;
            bool  ev  = (s & 1) == 0;
            float low = -16.f + (float)(s>>1);
            float cnt = ev ? nup : ndn;
            float mocc = (16.f > cnt) ? 1.f : 0.f;
            float mun  = (low  < cnt) ? 1.f : 0.f;
            float mx = fmaxf(l0,l1);
            float e0 = __expf(l0-mx), e1 = __expf(l1-mx);
            float inv = __builtin_amdgcn_rcpf(e0+e1);
            float a0s = __builtin_amdgcn_sqrtf(e0*inv)*mun;
            float a1s = __builtin_amdgcn_sqrtf(e1*inv)*mocc;
            float nrm = __builtin_amdgcn_sqrtf(a0s*a0s + a1s*a1s);
            float den = fmaxf(nrm, 1e-12f);
            float rden = __builtin_amdgcn_rcpf(den);
            a0s*=rden; a1s*=rden;
            const float PI_F = 3.14159265358979323846f;
            float p0 = PI_F*l0*__builtin_amdgcn_rcpf(1.f+fabsf(l0));
            float p1 = PI_F*l1*__builtin_amdgcn_rcpf(1.f+fabsf(l1));
            int bit = (int)((bitsM[srow] >> s) & 1ull);
            amp *= bit ? a1s : a0s;
            ph  += bit ? p1 : p0;
            if (ev) nup += (float)bit; else ndn += (float)bit;
        }

        // ---- chunk kh=0: MFMAs ----
        #pragma unroll
        for (int k2=0;k2<4;++k2){
            int kt = k2;
            half8 b0r = *(const half8*)(wlds + WOFF(0, 0+hv, kt) + L*8);
            half8 b0z = *(const half8*)(wlds + WOFF(0, 2+hv, kt) + L*8);
            half8 b0n = *(const half8*)(wlds + WOFF(0, 4+hv, kt) + L*8);
            half8 b1r = *(const half8*)(wlds + WOFF(1, 0+hv, kt) + L*8);
            half8 b1z = *(const half8*)(wlds + WOFF(1, 2+hv, kt) + L*8);
            half8 b1n = *(const half8*)(wlds + WOFF(1, 4+hv, kt) + L*8);
            half8 b2r = *(const half8*)(wlds + WOFF(2, 0+hv, kt) + L*8);
            half8 b2z = *(const half8*)(wlds + WOFF(2, 2+hv, kt) + L*8);
            half8 b2n = *(const half8*)(wlds + WOFF(2, 4+hv, kt) + L*8);
            #pragma unroll
            for (int m2=0;m2<2;++m2){
                a0n[0][m2] = __builtin_amdgcn_mfma_f32_16x16x32_f16(A0a[k2][m2], b0r, a0n[0][m2],0,0,0);
                a0n[1][m2] = __builtin_amdgcn_mfma_f32_16x16x32_f16(A0a[k2][m2], b0z, a0n[1][m2],0,0,0);
                a0n[2][m2] = __builtin_amdgcn_mfma_f32_16x16x32_f16(A0a[k2][m2], b0n, a0n[2][m2],0,0,0);
                aR [m2]    = __builtin_amdgcn_mfma_f32_16x16x32_f16(A0a[k2][m2], b1r, aR [m2],0,0,0);
                aZ [m2]    = __builtin_amdgcn_mfma_f32_16x16x32_f16(A0a[k2][m2], b1z, aZ [m2],0,0,0);
                aNI[m2]    = __builtin_amdgcn_mfma_f32_16x16x32_f16(A0a[k2][m2], b1n, aNI[m2],0,0,0);
                aR [m2]    = __builtin_amdgcn_mfma_f32_16x16x32_f16(A1a[k2][m2], b2r, aR [m2],0,0,0);
                aZ [m2]    = __builtin_amdgcn_mfma_f32_16x16x32_f16(A1a[k2][m2], b2z, aZ [m2],0,0,0);
                aNH[m2]    = __builtin_amdgcn_mfma_f32_16x16x32_f16(A1a[k2][m2], b2n, aNH[m2],0,0,0);
            }
        }

        // ---- chunk kh=1: loads then MFMAs ----
        half8 A0b[4][2], A1b[4][2];
        #pragma unroll
        for (int k2=0;k2<4;++k2){
            int kt = 4+k2;
            A0b[k2][0] = ldA(Hs0 +         kt*32 + quad*8);
            A0b[k2][1] = ldA(Hs0 + 16*HH + kt*32 + quad*8);
            A1b[k2][0] = ldA(Hs1 +         kt*32 + quad*8);
            A1b[k2][1] = ldA(Hs1 + 16*HH + kt*32 + quad*8);
        }
        #pragma unroll
        for (int k2=0;k2<4;++k2){
            int kt = 4+k2;
            half8 b0r = *(const half8*)(wlds + WOFF(0, 0+hv, kt) + L*8);
            half8 b0z = *(const half8*)(wlds + WOFF(0, 2+hv, kt) + L*8);
            half8 b0n = *(const half8*)(wlds + WOFF(0, 4+hv, kt) + L*8);
            half8 b1r = *(const half8*)(wlds + WOFF(1, 0+hv, kt) + L*8);
            half8 b1z = *(const half8*)(wlds + WOFF(1, 2+hv, kt) + L*8);
            half8 b1n = *(const half8*)(wlds + WOFF(1, 4+hv, kt) + L*8);
            half8 b2r = *(const half8*)(wlds + WOFF(2, 0+hv, kt) + L*8);
            half8 b2z = *(const half8*)(wlds + WOFF(2, 2+hv, kt) + L*8);
            half8 b2n = *(const half8*)(wlds + WOFF(2, 4+hv, kt) + L*8);
            #pragma unroll
            for (int m2=0;m2<2;++m2){
                a0n[0][m2] = __builtin_amdgcn_mfma_f32_16x16x32_f16(A0b[k2][m2], b0r, a0n[0][m2],0,0,0);
                a0n[1][m2] = __builtin_amdgcn_mfma_f32_16x16x32_f16(A0b[k2][m2], b0z, a0n[1][m2],0,0,0);
                a0n[2][m2] = __builtin_amdgcn_mfma_f32_16x16x32_f16(A0b[k2][m2], b0n, a0n[2][m2],0,0,0);
                aR [m2]    = __builtin_amdgcn_mfma_f32_16x16x32_f16(A0b[k2][m2], b1r, aR [m2],0,0,0);
                aZ [m2]    = __builtin_amdgcn_mfma_f32_16x16x32_f16(A0b[k2][m2], b1z, aZ [m2],0,0,0);
                aNI[m2]    = __builtin_amdgcn_mfma_f32_16x16x32_f16(A0b[k2][m2], b1n, aNI[m2],0,0,0);
                aR [m2]    = __builtin_amdgcn_mfma_f32_16x16x32_f16(A1b[k2][m2], b2r, aR [m2],0,0,0);
                aZ [m2]    = __builtin_amdgcn_mfma_f32_16x16x32_f16(A1b[k2][m2], b2z, aZ [m2],0,0,0);
                aNH[m2]    = __builtin_amdgcn_mfma_f32_16x16x32_f16(A1b[k2][m2], b2n, aNH[m2],0,0,0);
            }
        }

        // ---- ew1(i): h1n(i) -> H1[i&1] ----
        {
            _Float16* wp = H1 + (i&1)*(BTC*HH) + (32*mp + 4*quad)*HH + (j*32 + hv*16 + lm);
            #pragma unroll
            for (int m2=0;m2<2;++m2){
                #pragma unroll
                for (int reg=0;reg<4;++reg){
                    float r = sigmoidf_(aR[m2][reg]);
                    float z = sigmoidf_(aZ[m2][reg]);
                    float n = tanhf_(aNI[m2][reg] + r*aNH[m2][reg]);
                    float hnew = (1.f-z)*n + z*hr1[m2][reg];
                    hr1[m2][reg] = hnew;
                    stH(wp + (16*m2 + reg)*HH, hnew);
                }
            }
        }

        // ---- ew0(i+1): h0n(i+1) -> H0[(i+1)&1] (skip useless last one) ----
        if (i < SS-1){
            _Float16* wp = H0 + ((i+1)&1)*(BTC*HH) + (32*mp + 4*quad)*HH + (j*32 + hv*16 + lm);
            #pragma unroll
            for (int m2=0;m2<2;++m2){
                #pragma unroll
                for (int reg=0;reg<4;++reg){
                    int rowL = 32*mp + 16*m2 + 4*quad + reg;
                    int bit = (int)((bitsM[rowL] >> i) & 1ull);
                    float gr = bit?g0w[1]:g0w[0];
                    float gz = bit?g0w[3]:g0w[2];
                    float gn = bit?g0w[5]:g0w[4];
                    float r = sigmoidf_(gr + a0n[0][m2][reg]);
                    float z = sigmoidf_(gz + a0n[1][m2][reg]);
                    float n = tanhf_(gn + r*a0n[2][m2][reg]);
                    float hnew = (1.f-z)*n + z*hr0[m2][reg];
                    hr0[m2][reg] = hnew;
                    stH(wp + (16*m2 + reg)*HH, hnew);
                }
            }
        }

        // ---- arrive bar(i): publishes h1n(i), h0n(i+1) ----
        asm volatile("s_waitcnt vmcnt(0)" ::: "memory");   // write-throughs at IC
        __syncthreads();
        if (t==0)
            __hip_atomic_fetch_add(&flg[i],1,__ATOMIC_RELAXED,__HIP_MEMORY_SCOPE_AGENT);
    }

    // ---- epilogue: wait bar(63), sampling(63) ----
    if (t==0){
        int guard=0;
        while(__hip_atomic_load(&flg[SS-1],__ATOMIC_RELAXED,__HIP_MEMORY_SCOPE_AGENT) < CW){
            __builtin_amdgcn_s_sleep(1);
            if (++guard > (1<<20)) break;
        }
    }
    __syncthreads();
    {
        const int s = SS-1;
        const _Float16* Hn = H1 + (s&1)*(BTC*HH) + srow*HH + cs*8;
        half8 hvv = ldA(Hn);
        float s0=0.f, s1=0.f;
        #pragma unroll
        for (int e=0;e<8;++e){ float f=(float)hvv[e]; s0+=f*wl0[e]; s1+=f*wl1[e]; }
        #pragma unroll
        for (int off=16; off>0; off>>=1){ s0+=__shfl_xor(s0,off,32); s1+=__shfl_xor(s1,off,32); }
        float l0=s0+bl0, l1=s1+bl1;
        bool  ev  = (s & 1) == 0;
        float low = -16.f + (float)(s>>1);
        float cnt = ev ? nup : ndn;
        float mocc = (16.f > cnt) ? 1.f : 0.f;
        float mun  = (low  < cnt) ? 1.f : 0.f;
        float mx = fmaxf(l0,l1);
        float e0 = __expf(l0-mx), e1 = __expf(l1-mx);
        float inv = __builtin_amdgcn_rcpf(e0+e1);
        float a0s = __builtin_amdgcn_sqrtf(e0*inv)*mun;
        float a1s = __builtin_amdgcn_sqrtf(e1*inv)*mocc;
        float nrm = __builtin_amdgcn_sqrtf(a0s*a0s + a1s*a1s);
        float den = fmaxf(nrm, 1e-12f);
        float rden = __builtin_amdgcn_rcpf(den);
        a0s*=rden; a1s*=rden;
        const float PI_F = 3.14159265358979323846f;
        float p0 = PI_F*l0*__builtin_amdgcn_rcpf(1.f+fabsf(l0));
        float p1 = PI_F*l1*__builtin_amdgcn_rcpf(1.f+fabsf(l1));
        int bit = (int)((bitsM[srow] >> s) & 1ull);
        amp *= bit ? a1s : a0s;
        ph  += bit ? p1 : p0;
    }
    if (cs == 0) out[c*BTC + srow] = amp * cosf(ph);
}

extern "C" void kernel_launch(void* const* d_in, const int* in_sizes, int n_in,
                              void* d_out, int out_size, void* d_ws, size_t ws_size,
                              hipStream_t stream) {
    (void)in_sizes; (void)n_in; (void)out_size; (void)ws_size;
    const int*   x    = (const int*)d_in[0];
    const float* Wih0 = (const float*)d_in[1];
    const float* Whh0 = (const float*)d_in[2];
    const float* Wih1 = (const float*)d_in[3];
    const float* Whh1 = (const float*)d_in[4];
    const float* Wl   = (const float*)d_in[5];
    const float* bl   = (const float*)d_in[6];

    int*      flags = (int*)d_ws;                         // 8 KB used, 64 KB reserved
    _Float16* Hbuf  = (_Float16*)((char*)d_ws + 65536);   // 8 MB h state

    zero_flags<<<(NCL*SS + 255)/256, 256, 0, stream>>>(flags);
    rnn_cluster<<<NCL*CW, NT, 0, stream>>>(x, Wih0, Whh0, Wih1, Whh1, Wl, bl,
                                           (float*)d_out, flags, Hbuf);
}